// Round 5
// baseline (121.318 us; speedup 1.0000x reference)
//
#include <hip/hip_runtime.h>
#include <hip/hip_cooperative_groups.h>

namespace cg = cooperative_groups;

#define DENSE 2048
#define BATCH 64
#define MAXS  1024

typedef __attribute__((ext_vector_type(8))) __bf16 bf16x8;
typedef __attribute__((ext_vector_type(4))) float f32x4;

// ws: Cbf[b][k] bf16 counts in MFMA A-fragment order (verified R2, absmax 1.0):
//   lane = (b&15) | (((k>>3)&3)<<4) holds C[b = mt*16+(lane&15)][k = ks*32+(lane>>4)*8+i]
//   == A[m=lane&15][k=(lane>>4)*8+i] for mfma_f32_16x16x32_bf16.
//
// Single cooperative kernel, 256 blocks x 256 threads (1 block/CU co-resident:
// LDS 24KB, VGPR ~90 -- co-residency trivially satisfied).
// Phase 1: blocks 0-63 histogram their batch -> Cbf; blocks 64-255 zero `out`
//          and prefetch W (1 dword per 64B line) to flush the harness's dirty
//          0xAA poison out of L2/L3 concurrently with hist.
// grid.sync()
// Phase 2: block = (j-tile of 16, k-half of 1024); 4 waves x 8 k-steps, depth-2
//          register pipeline; LDS cross-wave reduce; atomicAdd (2 contenders).

__global__ __launch_bounds__(256) void fused_kernel(const int* __restrict__ ids,
                                                    const int* __restrict__ ns,
                                                    const float* __restrict__ W,
                                                    __bf16* __restrict__ Cbf,
                                                    float* __restrict__ out) {
    __shared__ int cnt[DENSE];            // 8 KB (phase 1, hist blocks)
    __shared__ float P[4][4][4][64];      // 16 KB (phase 2 reduce)

    const int tid = threadIdx.x;
    const int bid = blockIdx.x;

    // ---------------- Phase 1 ----------------
    if (bid < BATCH) {
        const int b = bid;
        #pragma unroll
        for (int k = tid; k < DENSE; k += 256) cnt[k] = 0;
        __syncthreads();
        const int n = ns[b];
        for (int i = tid; i < n; i += 256) {
            atomicAdd(&cnt[ids[b * MAXS + i]], 1);
        }
        __syncthreads();
        const int mt = b >> 4;
        const int bl = b & 15;
        #pragma unroll
        for (int k = tid; k < DENSE; k += 256) {
            const int lane = bl | (((k >> 3) & 3) << 4);
            const size_t off = (size_t)(((k >> 5) * 4 + mt) * 64 + lane) * 8 + (k & 7);
            Cbf[off] = (__bf16)(float)cnt[k];
        }
    } else {
        const int t = (bid - BATCH) * 256 + tid;      // 0..49151
        // zero out[] (32768 float4 chunks) for phase-2 atomics
        if (t < (BATCH * DENSE) / 4) ((f32x4*)out)[t] = (f32x4)0.0f;
        // prefetch W: touch one dword per 64B line -> pulls W into L2/L3 and
        // forces dirty-poison writebacks to overlap phase 1
        float s = 0.0f;
        for (int i = t; i < (DENSE * DENSE) / 16; i += 192 * 256) {
            s += W[(size_t)i * 16];
        }
        if (s != s) out[0] = s;   // never true (W finite); defeats DCE
    }

    cg::this_grid().sync();

    // ---------------- Phase 2 ----------------
    const int lane = tid & 63;
    const int wv   = tid >> 6;            // 0..3
    const int jt   = bid >> 1;            // 0..127
    const int kh   = bid & 1;             // k half
    const int j0   = jt * 16;
    const int ln   = lane & 15;           // j index (B-frag n)
    const int lq   = lane >> 4;           // k quad

    const float* wrow = W + (size_t)(j0 + ln) * DENSE;
    const int ks0 = kh * 32 + wv * 8;     // global 32k-step index, 8 steps/wave

    f32x4 acc[4];
    #pragma unroll
    for (int mt = 0; mt < 4; ++mt) acc[mt] = (f32x4)0.0f;

    f32x4 cw0, cw1, nw0, nw1;
    bf16x8 ca[4], na[4];

    // prologue: load step 0
    {
        const int kb = ks0 * 32 + lq * 8;
        cw0 = *(const f32x4*)(wrow + kb);
        cw1 = *(const f32x4*)(wrow + kb + 4);
        #pragma unroll
        for (int mt = 0; mt < 4; ++mt)
            ca[mt] = *(const bf16x8*)(Cbf + ((size_t)(ks0 * 4 + mt) * 64 + lane) * 8);
    }

    #pragma unroll
    for (int s = 0; s < 8; ++s) {
        if (s < 7) {                       // prefetch next step
            const int ks = ks0 + s + 1;
            const int kb = ks * 32 + lq * 8;
            nw0 = *(const f32x4*)(wrow + kb);
            nw1 = *(const f32x4*)(wrow + kb + 4);
            #pragma unroll
            for (int mt = 0; mt < 4; ++mt)
                na[mt] = *(const bf16x8*)(Cbf + ((size_t)(ks * 4 + mt) * 64 + lane) * 8);
        }
        bf16x8 wb;
        #pragma unroll
        for (int i = 0; i < 4; ++i) {
            wb[i]     = (__bf16)cw0[i];
            wb[i + 4] = (__bf16)cw1[i];
        }
        #pragma unroll
        for (int mt = 0; mt < 4; ++mt) {
            acc[mt] = __builtin_amdgcn_mfma_f32_16x16x32_bf16(ca[mt], wb, acc[mt], 0, 0, 0);
        }
        cw0 = nw0; cw1 = nw1;
        #pragma unroll
        for (int mt = 0; mt < 4; ++mt) ca[mt] = na[mt];
    }

    // cross-wave LDS reduction, conflict-free layout P[wv][mt][r][lane]
    #pragma unroll
    for (int mt = 0; mt < 4; ++mt) {
        #pragma unroll
        for (int r = 0; r < 4; ++r) {
            P[wv][mt][r][lane] = acc[mt][r];
        }
    }
    __syncthreads();

    const int jloc  = tid & 15;
    const int bpart = tid >> 4;                       // 0..15
    const int lsrc  = ((bpart >> 2) << 4) | jloc;     // source lane
    const int r     = bpart & 3;                      // source acc reg
    #pragma unroll
    for (int mt = 0; mt < 4; ++mt) {
        const float v = P[0][mt][r][lsrc] + P[1][mt][r][lsrc]
                      + P[2][mt][r][lsrc] + P[3][mt][r][lsrc];
        atomicAdd(&out[(size_t)(mt * 16 + bpart) * DENSE + j0 + jloc], v);
    }
}

extern "C" void kernel_launch(void* const* d_in, const int* in_sizes, int n_in,
                              void* d_out, int out_size, void* d_ws, size_t ws_size,
                              hipStream_t stream) {
    const int*   ids = (const int*)d_in[0];   // [64, 1024] int32
    const int*   ns  = (const int*)d_in[1];   // [64] int32
    const float* W   = (const float*)d_in[2]; // [2048, 2048] float32
    float*  out = (float*)d_out;              // [64, 2048] float32
    __bf16* Cbf = (__bf16*)d_ws;              // 64*2048 bf16 = 256 KB

    void* args[] = {(void*)&ids, (void*)&ns, (void*)&W, (void*)&Cbf, (void*)&out};
    hipLaunchCooperativeKernel((const void*)fused_kernel, dim3(256), dim3(256),
                               args, 0, stream);
}

// Round 6
// 72.159 us; speedup vs baseline: 1.6813x; 1.6813x over previous
//
#include <hip/hip_runtime.h>

#define DENSE 2048
#define BATCH 64
#define MAXS  1024

typedef __attribute__((ext_vector_type(8))) __bf16 bf16x8;
typedef __attribute__((ext_vector_type(4))) float f32x4;

// ws: Cbf[b][k] bf16 counts in MFMA A-fragment order (verified R2, absmax 1.0):
//   lane = (b&15) | (((k>>3)&3)<<4) holds C[b = mt*16+(lane&15)][k = ks*32+(lane>>4)*8+i]
//   == A[m=lane&15][k=(lane>>4)*8+i] for mfma_f32_16x16x32_bf16.

__global__ __launch_bounds__(256) void hist_kernel(const int* __restrict__ ids,
                                                   const int* __restrict__ ns,
                                                   __bf16* __restrict__ Cbf,
                                                   float* __restrict__ out) {
    __shared__ int cnt[DENSE];
    const int b = blockIdx.x;
    const int tid = threadIdx.x;
    #pragma unroll
    for (int k = tid; k < DENSE; k += 256) cnt[k] = 0;
    __syncthreads();
    const int n = ns[b];
    // 1024 spikes = exactly one int4 per thread
    const int4 v = ((const int4*)(ids + b * MAXS))[tid];
    const int base = tid * 4;
    if (base + 0 < n) atomicAdd(&cnt[v.x], 1);
    if (base + 1 < n) atomicAdd(&cnt[v.y], 1);
    if (base + 2 < n) atomicAdd(&cnt[v.z], 1);
    if (base + 3 < n) atomicAdd(&cnt[v.w], 1);
    __syncthreads();
    const int mt = b >> 4;
    const int bl = b & 15;
    #pragma unroll
    for (int k = tid; k < DENSE; k += 256) {
        const int lane = bl | (((k >> 3) & 3) << 4);
        const size_t off = (size_t)(((k >> 5) * 4 + mt) * 64 + lane) * 8 + (k & 7);
        Cbf[off] = (__bf16)(float)cnt[k];
        out[(size_t)b * DENSE + k] = 0.0f;   // zero output for spmm's atomics
    }
}

// spmm: out[b][j] += sum_k C[b][k] * W[j][k] via bf16 MFMA 16x16x32.
// Proven R2 structure: grid (128 j-tiles, 4 k-splits), 4 waves/block, 4
// k-steps/wave. Changes vs R2: W loads issued before A loads (W = HBM long
// pole, A = L2-hit), conflict-free epilogue LDS layout (R5: 35K vs 65K
// SQ_LDS_BANK_CONFLICT). Note: blockIdx linearization puts a j-tile's 4
// k-splits at bid, bid+128, bid+256, bid+384 — all congruent mod 8, so under
// round-robin XCD placement the 4 atomic contenders already share an XCD/L2.
__global__ __launch_bounds__(256) void spmm_kernel(const float* __restrict__ W,
                                                   const __bf16* __restrict__ Cbf,
                                                   float* __restrict__ out) {
    const int tid  = threadIdx.x;
    const int lane = tid & 63;
    const int wv   = tid >> 6;          // 0..3
    const int j0   = blockIdx.x * 16;   // j tile
    const int ks4  = blockIdx.y;        // 0..3 k split

    const int ln = lane & 15;           // j index within tile (B-frag n)
    const int lq = lane >> 4;           // k quad 0..3

    const int step0 = ks4 * 16 + wv * 4;
    const float* wrow = W + (size_t)(j0 + ln) * DENSE;

    // --- W loads first (HBM long pole; plain cached loads — NT regressed R3)
    f32x4 w0[4], w1[4];
    #pragma unroll
    for (int s = 0; s < 4; ++s) {
        const int kbase = (step0 + s) * 32 + lq * 8;
        w0[s] = *(const f32x4*)(wrow + kbase);
        w1[s] = *(const f32x4*)(wrow + kbase + 4);
    }
    // --- A-frag loads (Cbf is L2/L3-resident; R5 FETCH ≈ W only confirms)
    bf16x8 afr[4][4];
    #pragma unroll
    for (int s = 0; s < 4; ++s) {
        #pragma unroll
        for (int mt = 0; mt < 4; ++mt) {
            afr[s][mt] = *(const bf16x8*)(Cbf + ((size_t)((step0 + s) * 4 + mt) * 64 + lane) * 8);
        }
    }

    bf16x8 wb[4];
    #pragma unroll
    for (int s = 0; s < 4; ++s) {
        #pragma unroll
        for (int i = 0; i < 4; ++i) {
            wb[s][i]     = (__bf16)w0[s][i];
            wb[s][i + 4] = (__bf16)w1[s][i];
        }
    }

    f32x4 acc[4];
    #pragma unroll
    for (int mt = 0; mt < 4; ++mt) acc[mt] = (f32x4)0.0f;
    #pragma unroll
    for (int s = 0; s < 4; ++s) {
        #pragma unroll
        for (int mt = 0; mt < 4; ++mt) {
            acc[mt] = __builtin_amdgcn_mfma_f32_16x16x32_bf16(afr[s][mt], wb[s], acc[mt], 0, 0, 0);
        }
    }

    // --- cross-wave reduction, conflict-free layout P[wv][mt][r][lane]
    __shared__ float P[4][4][4][64];    // 16 KB
    #pragma unroll
    for (int mt = 0; mt < 4; ++mt) {
        #pragma unroll
        for (int r = 0; r < 4; ++r) {
            P[wv][mt][r][lane] = acc[mt][r];
        }
    }
    __syncthreads();

    // thread t -> (jloc = t&15 fastest for coalesced atomics, bpart = t>>4)
    const int jloc  = tid & 15;
    const int bpart = tid >> 4;                       // 0..15
    const int lsrc  = ((bpart >> 2) << 4) | jloc;     // source lane
    const int r     = bpart & 3;                      // source acc reg
    #pragma unroll
    for (int mt = 0; mt < 4; ++mt) {
        const float v = P[0][mt][r][lsrc] + P[1][mt][r][lsrc]
                      + P[2][mt][r][lsrc] + P[3][mt][r][lsrc];
        atomicAdd(&out[(size_t)(mt * 16 + bpart) * DENSE + j0 + jloc], v);
    }
}

extern "C" void kernel_launch(void* const* d_in, const int* in_sizes, int n_in,
                              void* d_out, int out_size, void* d_ws, size_t ws_size,
                              hipStream_t stream) {
    const int*   ids = (const int*)d_in[0];   // [64, 1024] int32
    const int*   ns  = (const int*)d_in[1];   // [64] int32
    const float* W   = (const float*)d_in[2]; // [2048, 2048] float32
    float*  out = (float*)d_out;              // [64, 2048] float32
    __bf16* Cbf = (__bf16*)d_ws;              // 64*2048 bf16 = 256 KB

    hipLaunchKernelGGL(hist_kernel, dim3(BATCH), dim3(256), 0, stream, ids, ns, Cbf, out);
    hipLaunchKernelGGL(spmm_kernel, dim3(128, 4), dim3(256), 0, stream, W, Cbf, out);
}